// Round 4
// baseline (1919.963 us; speedup 1.0000x reference)
//
#include <hip/hip_runtime.h>

#define NPTS 60000
#define C 128
#define K 32
#define FF 512
#define CO 128
#define H 8
#define DH 16
#define EPS 1e-5f

// ---- fp32 weight layout (float elements) ----
constexpr int OFF_INPROJ_W = 0;          // 384*128
constexpr int OFF_INPROJ_B = 49152;      // 384
constexpr int OFF_OUT_W    = 49536;      // 16384
constexpr int OFF_OUT_B    = 65920;      // 128
constexpr int OFF_QPOS_W   = 66048;      // 384
constexpr int OFF_QPOS_B   = 66432;      // 128
constexpr int OFF_KPOS_W   = 66560;      // 384
constexpr int OFF_KPOS_B   = 66944;      // 128
constexpr int OFF_N1G      = 67072;
constexpr int OFF_N1B      = 67200;
constexpr int OFF_N2G      = 67328;
constexpr int OFF_N2B      = 67456;
constexpr int OFF_LIN1_W   = 67584;      // 65536
constexpr int OFF_LIN1_B   = 133120;     // 512
constexpr int OFF_LIN2_W   = 133632;     // 65536
constexpr int OFF_LIN2_B   = 199168;     // 128
constexpr int OFF_OUTL_W   = 199296;     // 16384
constexpr int OFF_OUTL_B   = 215680;     // 128
constexpr int OFF_BOG      = 215808;
constexpr int OFF_BOB      = 215936;
constexpr int WTOTAL       = 216064;

// ---- bf16 weight copies (ushort elements within wsB) ----
constexpr int B_INPROJ = 0;        // 384x128 rows: wq(0..127) wk(128..255) wv(256..383)
constexpr int B_OUTW   = 49152;    // 128x128
constexpr int B_LIN1   = 65536;    // 512x128
constexpr int B_LIN2   = 131072;   // 128x512
constexpr int B_OUTL   = 196608;   // 128x128
constexpr int B_WKT    = 212992;   // 128x128: wkT[c][r] = wk[r][c]  (r = inproj row 128+r)
constexpr size_t OFF_WB_BYTES  = 1587456;
constexpr size_t OFF_BIG_BYTES = 2046208;  // OFF_WB + 229376*2

typedef __attribute__((ext_vector_type(8))) short bfrag8;
typedef __attribute__((ext_vector_type(8))) unsigned short u16x8;
typedef __attribute__((ext_vector_type(4))) float f32x4;

__device__ __forceinline__ float bf2f(unsigned short s) {
    return __uint_as_float(((unsigned)s) << 16);
}
__device__ __forceinline__ unsigned short f2bf(float f) {
    unsigned u = __float_as_uint(f);
    u += 0x7fffu + ((u >> 16) & 1u);
    return (unsigned short)(u >> 16);
}
__device__ __forceinline__ float ldE(const float* p, long i) { return p[i]; }
__device__ __forceinline__ float ldE(const unsigned short* p, long i) { return bf2f(p[i]); }
__device__ __forceinline__ void stE(float* p, long i, float v) { p[i] = v; }
__device__ __forceinline__ void stE(unsigned short* p, long i, float v) { p[i] = f2bf(v); }
__device__ __forceinline__ float ldF(const void* p, long i, int bf) {
    return bf ? bf2f(((const unsigned short*)p)[i]) : ((const float*)p)[i];
}
__device__ __forceinline__ bfrag8 ldfrag(const unsigned short* base, int stride, int lane, int k0) {
    return *(const bfrag8*)(base + (lane & 15) * stride + k0 + ((lane >> 4) << 3));
}

// ---- dtype probe ----
__global__ __launch_bounds__(256) void k_detect(const unsigned short* __restrict__ f,
                                                int* __restrict__ flag) {
    __shared__ int cnt_s;
    if (threadIdx.x == 0) cnt_s = 0;
    __syncthreads();
    int sane = 0;
    for (int j = 0; j < 16; ++j) {
        unsigned short u = f[threadIdx.x * 16 + j];
        int e = (u >> 7) & 255;
        sane += (u == 0 || (e >= 100 && e <= 142)) ? 1 : 0;
    }
    atomicAdd(&cnt_s, sane);
    __syncthreads();
    if (threadIdx.x == 0) *flag = (cnt_s >= 3686) ? 1 : 0;
}

struct WTab {
    const void* src[20];
    int beg[20];
    int end[20];
    int bo[20];
};

__global__ __launch_bounds__(256) void k_cvt_weights(WTab tab, float* __restrict__ ws,
                                                     unsigned short* __restrict__ wsB,
                                                     const int* __restrict__ flagp) {
    int bf = *flagp;
    int gid = blockIdx.x * 256 + threadIdx.x;
    #pragma unroll
    for (int j = 0; j < 20; ++j) {
        if (gid >= tab.beg[j] && gid < tab.end[j]) {
            int off = gid - tab.beg[j];
            float v;
            unsigned short raw;
            if (bf) { raw = ((const unsigned short*)tab.src[j])[off]; v = bf2f(raw); }
            else    { v = ((const float*)tab.src[j])[off]; raw = f2bf(v); }
            ws[gid] = v;
            if (tab.bo[j] >= 0) wsB[tab.bo[j] + off] = raw;
            if (j == 0 && off >= 16384 && off < 32768) {   // wk rows -> transposed copy
                int r = (off >> 7) - 128;
                int c = off & 127;
                wsB[B_WKT + c * C + r] = raw;
            }
        }
    }
}

// ---- fused coords + qpos + QKV projection (MFMA, bf16 outputs) ----
template <typename T>
__global__ __launch_bounds__(256) void k_proj(
    const float* __restrict__ wsW, const unsigned short* __restrict__ wsB,
    const void* __restrict__ featv, const int* __restrict__ flagp,
    const int* __restrict__ indices, float* __restrict__ coords,
    T* __restrict__ Qh, T* __restrict__ Kf, T* __restrict__ Vf)
{
    __shared__ __align__(16) unsigned short sxb[32][136];
    __shared__ __align__(16) unsigned short sqb[32][136];
    __shared__ float scd[32][4];
    int t = threadIdx.x;
    int row0 = blockIdx.x * 32;
    const int bf = *flagp;
    if (t < 96) {
        int r = t / 3, j = t - 3 * r;
        int n = row0 + r;
        int srci = (j == 0) ? 3 : (j == 1 ? 2 : 1);
        float vs = (j == 2) ? 0.2f : 0.1f;
        float mn = (j == 2) ? -3.0f : -40.0f;
        float v = ((float)indices[n * 4 + srci] + 0.5f) * vs + mn;
        scd[r][j] = v;
        coords[n * 3 + j] = v;
    }
    __syncthreads();
    const float* qpw = wsW + OFF_QPOS_W;
    const float* qpb = wsW + OFF_QPOS_B;
    for (int i = t; i < 32 * C; i += 256) {
        int r = i >> 7, c = i & 127;
        float x = ldF(featv, (long)row0 * C + i, bf);
        float a = qpb[c] + scd[r][0]*qpw[c*3] + scd[r][1]*qpw[c*3+1] + scd[r][2]*qpw[c*3+2];
        sxb[r][c] = f2bf(x);
        sqb[r][c] = f2bf(x + fmaxf(a, 0.0f));
    }
    __syncthreads();
    int lane = t & 63, w = t >> 6;
    int col = lane & 15, quad = lane >> 4;
    for (int tid = w; tid < 16; tid += 4) {
        int mt = tid & 1, nt = tid >> 1, n0 = nt * 16;
        f32x4 acc = {0.f, 0.f, 0.f, 0.f};
        const unsigned short* aB = &sqb[mt*16][0];
        const unsigned short* bB = wsB + B_INPROJ + n0 * C;
        #pragma unroll
        for (int kt = 0; kt < 4; ++kt) {
            bfrag8 a = ldfrag(aB, 136, lane, kt*32);
            bfrag8 b = ldfrag(bB, C, lane, kt*32);
            acc = __builtin_amdgcn_mfma_f32_16x16x32_bf16(a, b, acc, 0, 0, 0);
        }
        #pragma unroll
        for (int r = 0; r < 4; ++r) {
            int m = row0 + mt*16 + quad*4 + r;
            int n = n0 + col;
            stE(Qh, (long)m * C + n, acc[r] + wsW[OFF_INPROJ_B + n]);
        }
    }
    for (int tid = w; tid < 32; tid += 4) {
        int mt = tid & 1, nt = tid >> 1;
        int ng0 = 128 + nt * 16;
        f32x4 acc = {0.f, 0.f, 0.f, 0.f};
        const unsigned short* aB = &sxb[mt*16][0];
        const unsigned short* bB = wsB + B_INPROJ + ng0 * C;
        #pragma unroll
        for (int kt = 0; kt < 4; ++kt) {
            bfrag8 a = ldfrag(aB, 136, lane, kt*32);
            bfrag8 b = ldfrag(bB, C, lane, kt*32);
            acc = __builtin_amdgcn_mfma_f32_16x16x32_bf16(a, b, acc, 0, 0, 0);
        }
        #pragma unroll
        for (int r = 0; r < 4; ++r) {
            int m = row0 + mt*16 + quad*4 + r;
            int ng = ng0 + col;
            float v = acc[r] + wsW[OFF_INPROJ_B + ng];
            if (ng < 256) stE(Kf, (long)m * C + (ng - 128), v);
            else          stE(Vf, (long)m * C + (ng - 256), v);
        }
    }
}

// ---- attention: 1 wave per point, 4 points per block (block = 64 threads) ----
// score[h][k] = (qh_h . Kf[g_k]_h  +  qkt_h . p_k) * 0.25 ; att = softmax . (Vf[g]+pv)
// qkt via masked-A mfma vs wkT; part2 & pv via mfma; p natural [k][c] is both B and A operand.
template <typename T>
__global__ __launch_bounds__(64) void k_attn(
    const float* __restrict__ wsW, const unsigned short* __restrict__ wsB,
    const float* __restrict__ coords, const int* __restrict__ key_idx,
    const unsigned short* __restrict__ Qh, const unsigned short* __restrict__ Kf,
    const unsigned short* __restrict__ Vf, T* __restrict__ Y)
{
    __shared__ __align__(16) unsigned short P[32][136];   // p[k][c] bf16
    __shared__ __align__(16) unsigned short R[32][136];   // qhA(0-15)/qkt(16-31) then pv(0-31)
    __shared__ float SC[8][36];                           // scores -> attn
    __shared__ float REL[32][4];
    __shared__ int   GS[32];
    __shared__ float CEN[4];

    int l = threadIdx.x;           // 0..63
    int col = l & 15, quad = l >> 4;
    int c0 = 2 * l, c1 = 2 * l + 1;

    const float* kpwp = wsW + OFF_KPOS_W;
    float kw00 = kpwp[c0*3], kw01 = kpwp[c0*3+1], kw02 = kpwp[c0*3+2];
    float kw10 = kpwp[c1*3], kw11 = kpwp[c1*3+1], kw12 = kpwp[c1*3+2];
    float kb0 = wsW[OFF_KPOS_B + c0], kb1 = wsW[OFF_KPOS_B + c1];
    const unsigned short* wkT = wsB + B_WKT;
    const unsigned short* wvp = wsB + B_INPROJ + 256 * C;

    for (int i = 0; i < 4; ++i) {
        int n = blockIdx.x * 4 + i;
        __syncthreads();
        // Ph0a: gather indices + center
        if (l < 32) GS[l] = key_idx[n * K + l];
        if (l >= 60 && l < 63) CEN[l - 60] = coords[n * 3 + (l - 60)];
        __syncthreads();
        // Ph0b: rel coords ; Ph2a: zero qhA rows 0-7
        if (l < 32) {
            int gc = max(GS[l], 0);
            REL[l][0] = coords[gc*3+0] - CEN[0];
            REL[l][1] = coords[gc*3+1] - CEN[1];
            REL[l][2] = coords[gc*3+2] - CEN[2];
        }
        {
            unsigned* rz = (unsigned*)&R[0][0];
            #pragma unroll
            for (int z = 0; z < 9; ++z) {
                int idx = l + z * 64;
                if (idx < 544) rz[idx] = 0;    // 8 rows * 136 u16 = 544 dwords
            }
        }
        __syncthreads();
        // Ph2b: scatter qh into masked-A tile (row c>>4, col c)
        {
            unsigned v2 = ((const unsigned*)(Qh + (long)n * C))[l];
            *(unsigned*)&R[c0 >> 4][c0] = v2;
        }
        // Ph1: build p[k][c] (lane owns c0,c1)
        for (int k = 0; k < 32; ++k) {
            float4 rr = *(const float4*)&REL[k][0];
            float p0 = fmaxf(kb0 + rr.x*kw00 + rr.y*kw01 + rr.z*kw02, 0.f);
            float p1 = fmaxf(kb1 + rr.x*kw10 + rr.y*kw11 + rr.z*kw12, 0.f);
            unsigned pk = (unsigned)f2bf(p0) | ((unsigned)f2bf(p1) << 16);
            *(unsigned*)&P[k][c0] = pk;
        }
        __syncthreads();
        // Ph3: qkt[h][c] = sum_c' qhA[h][c'] * wk[c'][c]   (A masked, B = wkT)
        bfrag8 aq[4];
        #pragma unroll
        for (int ks = 0; ks < 4; ++ks)
            aq[ks] = *(const bfrag8*)(&R[0][0] + col * 136 + ks * 32 + quad * 8);
        #pragma unroll
        for (int nt = 0; nt < 8; ++nt) {
            f32x4 d = {0.f, 0.f, 0.f, 0.f};
            #pragma unroll
            for (int ks = 0; ks < 4; ++ks) {
                bfrag8 b = *(const bfrag8*)(wkT + (nt * 16 + col) * C + ks * 32 + quad * 8);
                d = __builtin_amdgcn_mfma_f32_16x16x32_bf16(aq[ks], b, d, 0, 0, 0);
            }
            #pragma unroll
            for (int r = 0; r < 4; ++r)
                R[16 + quad * 4 + r][nt * 16 + col] = f2bf(d[r]);
        }
        // Ph4: part1[h][k] = qh_h . Kf[g_k]_h  (VALU, bf16 gathers)
        #pragma unroll
        for (int it = 0; it < 4; ++it) {
            int id = l + 64 * it;
            int k = id >> 3, h = id & 7;
            int gc = max(GS[k], 0);
            const u16x8* q8 = (const u16x8*)(&R[h][h * 16]);
            const u16x8* f8 = (const u16x8*)(Kf + (long)gc * C + h * 16);
            u16x8 qa = q8[0], qb = q8[1], fa = f8[0], fb = f8[1];
            float acc = 0.f;
            #pragma unroll
            for (int j = 0; j < 8; ++j) acc += bf2f(qa[j]) * bf2f(fa[j]);
            #pragma unroll
            for (int j = 0; j < 8; ++j) acc += bf2f(qb[j]) * bf2f(fb[j]);
            SC[h][k] = acc;
        }
        __syncthreads();
        // Ph5: part2 = qkt . p ; finalize scores with mask + scale
        bfrag8 ak[4];
        #pragma unroll
        for (int ks = 0; ks < 4; ++ks)
            ak[ks] = *(const bfrag8*)(&R[16][0] + col * 136 + ks * 32 + quad * 8);
        #pragma unroll
        for (int nt = 0; nt < 2; ++nt) {
            f32x4 d = {0.f, 0.f, 0.f, 0.f};
            #pragma unroll
            for (int ks = 0; ks < 4; ++ks) {
                bfrag8 b = *(const bfrag8*)(&P[nt * 16][0] + col * 136 + ks * 32 + quad * 8);
                d = __builtin_amdgcn_mfma_f32_16x16x32_bf16(ak[ks], b, d, 0, 0, 0);
            }
            if (quad < 2) {
                #pragma unroll
                for (int r = 0; r < 4; ++r) {
                    int h = quad * 4 + r, k = nt * 16 + col;
                    float sc = (SC[h][k] + d[r]) * 0.25f;
                    SC[h][k] = (GS[k] < 0) ? -1e30f : sc;
                }
            }
        }
        __syncthreads();
        // Ph6: softmax per h (8 lanes per h, 4 k's per lane, shuffle-reduce)
        {
            int h = l >> 3, sub = l & 7;
            float e0, e1, e2, e3;
            float v0 = SC[h][sub], v1 = SC[h][sub + 8], v2 = SC[h][sub + 16], v3 = SC[h][sub + 24];
            float m = fmaxf(fmaxf(v0, v1), fmaxf(v2, v3));
            m = fmaxf(m, __shfl_xor(m, 1));
            m = fmaxf(m, __shfl_xor(m, 2));
            m = fmaxf(m, __shfl_xor(m, 4));
            e0 = __expf(v0 - m); e1 = __expf(v1 - m); e2 = __expf(v2 - m); e3 = __expf(v3 - m);
            float s = e0 + e1 + e2 + e3;
            s += __shfl_xor(s, 1);
            s += __shfl_xor(s, 2);
            s += __shfl_xor(s, 4);
            float inv = 1.0f / s;
            SC[h][sub]      = e0 * inv;
            SC[h][sub + 8]  = e1 * inv;
            SC[h][sub + 16] = e2 * inv;
            SC[h][sub + 24] = e3 * inv;
        }
        __syncthreads();
        // Ph7: pv[k][c] = p_k . wv[c]  (A = p, B = wv natural)
        bfrag8 ap[2][4];
        #pragma unroll
        for (int mt = 0; mt < 2; ++mt)
            #pragma unroll
            for (int ks = 0; ks < 4; ++ks)
                ap[mt][ks] = *(const bfrag8*)(&P[mt * 16][0] + col * 136 + ks * 32 + quad * 8);
        #pragma unroll
        for (int nt = 0; nt < 8; ++nt) {
            f32x4 d0 = {0.f, 0.f, 0.f, 0.f}, d1 = {0.f, 0.f, 0.f, 0.f};
            #pragma unroll
            for (int ks = 0; ks < 4; ++ks) {
                bfrag8 b = *(const bfrag8*)(wvp + (nt * 16 + col) * C + ks * 32 + quad * 8);
                d0 = __builtin_amdgcn_mfma_f32_16x16x32_bf16(ap[0][ks], b, d0, 0, 0, 0);
                d1 = __builtin_amdgcn_mfma_f32_16x16x32_bf16(ap[1][ks], b, d1, 0, 0, 0);
            }
            #pragma unroll
            for (int r = 0; r < 4; ++r) {
                int c = nt * 16 + col;
                R[quad * 4 + r][c]      = f2bf(d0[r]);
                R[16 + quad * 4 + r][c] = f2bf(d1[r]);
            }
        }
        __syncthreads();
        // Ph8: att[c] = sum_k attn[h_c][k] * (Vf[g_k][c] + pv[k][c])
        {
            int h0 = l >> 4, h1 = h0 + 4;
            float a0 = 0.f, a1 = 0.f;
            for (int k = 0; k < 32; ++k) {
                int gc = max(GS[k], 0);
                float at0 = SC[h0][k], at1 = SC[h1][k];
                long vb = (long)gc * C;
                a0 += at0 * (bf2f(Vf[vb + l])      + bf2f(R[k][l]));
                a1 += at1 * (bf2f(Vf[vb + l + 64]) + bf2f(R[k][l + 64]));
            }
            stE(Y, (long)n * C + l, a0);
            stE(Y, (long)n * C + l + 64, a1);
        }
    }
}

// ---- out-proj + residual + bn1 stats (MFMA) ----
template <typename T>
__global__ __launch_bounds__(256) void k_outproj(
    const float* __restrict__ wsW, const unsigned short* __restrict__ wsB,
    const void* __restrict__ featv, const int* __restrict__ flagp,
    T* __restrict__ Y, float* __restrict__ acc_s)
{
    __shared__ __align__(16) unsigned short sab[32][136];
    __shared__ float syf[32][132];
    int t = threadIdx.x;
    int row0 = blockIdx.x * 32;
    const int bf = *flagp;
    for (int i = t; i < 32 * C; i += 256)
        sab[i>>7][i&127] = f2bf(ldE(Y, (long)row0 * C + i));
    __syncthreads();
    int lane = t & 63, w = t >> 6;
    int col = lane & 15, quad = lane >> 4;
    for (int tid = w; tid < 16; tid += 4) {
        int mt = tid & 1, nt = tid >> 1, n0 = nt * 16;
        f32x4 acc = {0.f, 0.f, 0.f, 0.f};
        const unsigned short* aB = &sab[mt*16][0];
        const unsigned short* bB = wsB + B_OUTW + n0 * C;
        #pragma unroll
        for (int kt = 0; kt < 4; ++kt) {
            bfrag8 a = ldfrag(aB, 136, lane, kt*32);
            bfrag8 b = ldfrag(bB, C, lane, kt*32);
            acc = __builtin_amdgcn_mfma_f32_16x16x32_bf16(a, b, acc, 0, 0, 0);
        }
        #pragma unroll
        for (int r = 0; r < 4; ++r) {
            int m = mt*16 + quad*4 + r;
            int n = n0 + col;
            syf[m][n] = acc[r] + wsW[OFF_OUT_B + n] + ldF(featv, (long)(row0+m)*C + n, bf);
        }
    }
    __syncthreads();
    for (int i = t; i < 32 * C; i += 256)
        stE(Y, (long)row0 * C + i, syf[i>>7][i&127]);
    if (t < C) {
        float s = 0.f, sq = 0.f;
        for (int r = 0; r < 32; ++r) { float v = syf[r][t]; s += v; sq += v*v; }
        atomicAdd(&acc_s[t], s);
        atomicAdd(&acc_s[C + t], sq);
    }
}

// ---- bn1 + FFN + residual + bn2 stats (MFMA) ----
template <typename T>
__global__ __launch_bounds__(256) void k_ffn(
    const float* __restrict__ wsW, const unsigned short* __restrict__ wsB,
    T* __restrict__ Y, const float* __restrict__ acc1, float* __restrict__ acc2)
{
    __shared__ __align__(16) unsigned short sxb[32][136];
    __shared__ __align__(16) unsigned short sh[32][520];
    __shared__ float nsc[C], nsh[C];
    float (*syf)[132] = (float(*)[132])sh;
    int t = threadIdx.x;
    int row0 = blockIdx.x * 32;
    if (t < C) {
        float m = acc1[t] * (1.0f/NPTS);
        float v = acc1[C+t] * (1.0f/NPTS) - m*m;
        float rs = rsqrtf(v + EPS);
        float sc = rs * wsW[OFF_N1G + t];
        nsc[t] = sc;
        nsh[t] = wsW[OFF_N1B + t] - m * sc;
    }
    __syncthreads();
    for (int i = t; i < 32 * C; i += 256) {
        int c = i & 127;
        sxb[i>>7][c] = f2bf(ldE(Y, (long)row0 * C + i) * nsc[c] + nsh[c]);
    }
    __syncthreads();
    int lane = t & 63, w = t >> 6;
    int col = lane & 15, quad = lane >> 4;
    for (int tid = w; tid < 64; tid += 4) {
        int mt = tid & 1, nt = tid >> 1, n0 = nt * 16;
        f32x4 acc = {0.f, 0.f, 0.f, 0.f};
        const unsigned short* aB = &sxb[mt*16][0];
        const unsigned short* bB = wsB + B_LIN1 + n0 * C;
        #pragma unroll
        for (int kt = 0; kt < 4; ++kt) {
            bfrag8 a = ldfrag(aB, 136, lane, kt*32);
            bfrag8 b = ldfrag(bB, C, lane, kt*32);
            acc = __builtin_amdgcn_mfma_f32_16x16x32_bf16(a, b, acc, 0, 0, 0);
        }
        #pragma unroll
        for (int r = 0; r < 4; ++r) {
            int m = mt*16 + quad*4 + r;
            int n = n0 + col;
            sh[m][n] = f2bf(fmaxf(acc[r] + wsW[OFF_LIN1_B + n], 0.f));
        }
    }
    __syncthreads();
    f32x4 accT[4];
    #pragma unroll
    for (int i = 0; i < 4; ++i) {
        int tid = w + 4*i;
        int mt = tid & 1, nt = tid >> 1, n0 = nt * 16;
        f32x4 acc = {0.f, 0.f, 0.f, 0.f};
        const unsigned short* aB = &sh[mt*16][0];
        const unsigned short* bB = wsB + B_LIN2 + n0 * FF;
        #pragma unroll
        for (int kt = 0; kt < 16; ++kt) {
            bfrag8 a = ldfrag(aB, 520, lane, kt*32);
            bfrag8 b = ldfrag(bB, FF, lane, kt*32);
            acc = __builtin_amdgcn_mfma_f32_16x16x32_bf16(a, b, acc, 0, 0, 0);
        }
        accT[i] = acc;
    }
    __syncthreads();
    #pragma unroll
    for (int i = 0; i < 4; ++i) {
        int tid = w + 4*i;
        int mt = tid & 1, nt = tid >> 1, n0 = nt * 16;
        #pragma unroll
        for (int r = 0; r < 4; ++r) {
            int m = mt*16 + quad*4 + r;
            int n = n0 + col;
            syf[m][n] = accT[i][r] + wsW[OFF_LIN2_B + n] + bf2f(sxb[m][n]);
        }
    }
    __syncthreads();
    for (int i = t; i < 32 * C; i += 256)
        stE(Y, (long)row0 * C + i, syf[i>>7][i&127]);
    if (t < C) {
        float s = 0.f, sq = 0.f;
        for (int r = 0; r < 32; ++r) { float v = syf[r][t]; s += v; sq += v*v; }
        atomicAdd(&acc2[t], s);
        atomicAdd(&acc2[C+t], sq);
    }
}

// ---- bn2 + output linear + bn3 stats (MFMA) ----
template <typename T>
__global__ __launch_bounds__(256) void k_outl(
    const float* __restrict__ wsW, const unsigned short* __restrict__ wsB,
    T* __restrict__ Y, const float* __restrict__ acc2, float* __restrict__ acc3)
{
    __shared__ __align__(16) unsigned short sxb[32][136];
    __shared__ float syf[32][132];
    __shared__ float nsc[C], nsh[C];
    int t = threadIdx.x;
    int row0 = blockIdx.x * 32;
    if (t < C) {
        float m = acc2[t] * (1.0f/NPTS);
        float v = acc2[C+t] * (1.0f/NPTS) - m*m;
        float rs = rsqrtf(v + EPS);
        float sc = rs * wsW[OFF_N2G + t];
        nsc[t] = sc;
        nsh[t] = wsW[OFF_N2B + t] - m * sc;
    }
    __syncthreads();
    for (int i = t; i < 32 * C; i += 256) {
        int c = i & 127;
        sxb[i>>7][c] = f2bf(ldE(Y, (long)row0 * C + i) * nsc[c] + nsh[c]);
    }
    __syncthreads();
    int lane = t & 63, w = t >> 6;
    int col = lane & 15, quad = lane >> 4;
    for (int tid = w; tid < 16; tid += 4) {
        int mt = tid & 1, nt = tid >> 1, n0 = nt * 16;
        f32x4 acc = {0.f, 0.f, 0.f, 0.f};
        const unsigned short* aB = &sxb[mt*16][0];
        const unsigned short* bB = wsB + B_OUTL + n0 * C;
        #pragma unroll
        for (int kt = 0; kt < 4; ++kt) {
            bfrag8 a = ldfrag(aB, 136, lane, kt*32);
            bfrag8 b = ldfrag(bB, C, lane, kt*32);
            acc = __builtin_amdgcn_mfma_f32_16x16x32_bf16(a, b, acc, 0, 0, 0);
        }
        #pragma unroll
        for (int r = 0; r < 4; ++r) {
            int m = mt*16 + quad*4 + r;
            int n = n0 + col;
            syf[m][n] = acc[r] + wsW[OFF_OUTL_B + n];
        }
    }
    __syncthreads();
    for (int i = t; i < 32 * CO; i += 256)
        stE(Y, (long)row0 * CO + i, syf[i>>7][i&127]);
    if (t < CO) {
        float s = 0.f, sq = 0.f;
        for (int r = 0; r < 32; ++r) { float v = syf[r][t]; s += v; sq += v*v; }
        atomicAdd(&acc3[t], s);
        atomicAdd(&acc3[CO+t], sq);
    }
}

// ---- final BN + relu -> output ----
template <typename T>
__global__ __launch_bounds__(256) void k_final(
    const float* __restrict__ wsW, const T* __restrict__ Y,
    const float* __restrict__ acc3, const int* __restrict__ flagp,
    void* __restrict__ out)
{
    long i = (long)blockIdx.x * 256 + threadIdx.x;
    int c = (int)(i & (CO-1));
    float m = acc3[c] * (1.0f/NPTS);
    float v = acc3[CO+c] * (1.0f/NPTS) - m*m;
    float rs = rsqrtf(v + EPS);
    float y = (ldE(Y, i) - m) * rs * wsW[OFF_BOG + c] + wsW[OFF_BOB + c];
    y = fmaxf(y, 0.f);
    if (*flagp) ((unsigned short*)out)[i] = f2bf(y);
    else        ((float*)out)[i] = y;
}

extern "C" void kernel_launch(void* const* d_in, const int* in_sizes, int n_in,
                              void* d_out, int out_size, void* d_ws, size_t ws_size,
                              hipStream_t stream)
{
    char* base = (char*)d_ws;
    float* wsW = (float*)base;
    float* acc1 = wsW + WTOTAL;
    float* acc2 = acc1 + 256;
    float* acc3 = acc2 + 256;
    int* flagp = (int*)(wsW + WTOTAL + 768);
    float* coords = wsW + WTOTAL + 776;
    unsigned short* wsB = (unsigned short*)(base + OFF_WB_BYTES);

    const void* featv = d_in[0];
    const int* indices = (const int*)d_in[1];
    const int* key_idx = (const int*)d_in[2];

    hipMemsetAsync(acc1, 0, 768 * sizeof(float), stream);
    k_detect<<<1, 256, 0, stream>>>((const unsigned short*)d_in[0], flagp);

    static const int cnt[20] = {49152,384,16384,128,384,128,384,128,128,128,
                                128,128,65536,512,65536,128,16384,128,128,128};
    static const int bofs[20] = {B_INPROJ,-1,B_OUTW,-1,-1,-1,-1,-1,-1,-1,
                                 -1,-1,B_LIN1,-1,B_LIN2,-1,B_OUTL,-1,-1,-1};
    WTab tab;
    int off = 0;
    for (int j = 0; j < 20; ++j) {
        tab.src[j] = d_in[3 + j];
        tab.beg[j] = off;
        tab.end[j] = off + cnt[j];
        tab.bo[j] = bofs[j];
        off += cnt[j];
    }
    k_cvt_weights<<<WTOTAL/256, 256, 0, stream>>>(tab, wsW, wsB, flagp);

    size_t bigN = (size_t)NPTS * C;
    bool f32mode = (ws_size >= OFF_BIG_BYTES + 3 * bigN * 2 + bigN * 4);

    unsigned short* Qh = (unsigned short*)(base + OFF_BIG_BYTES);
    unsigned short* Kf = Qh + bigN;
    unsigned short* Vf = Kf + bigN;

    k_proj<unsigned short><<<NPTS/32, 256, 0, stream>>>(wsW, wsB, featv, flagp, indices, coords, Qh, Kf, Vf);

    if (f32mode) {
        float* Y = (float*)(Vf + bigN);
        k_attn<float><<<NPTS/4, 64, 0, stream>>>(wsW, wsB, coords, key_idx, Qh, Kf, Vf, Y);
        k_outproj<float><<<NPTS/32, 256, 0, stream>>>(wsW, wsB, featv, flagp, Y, acc1);
        k_ffn<float><<<NPTS/32, 256, 0, stream>>>(wsW, wsB, Y, acc1, acc2);
        k_outl<float><<<NPTS/32, 256, 0, stream>>>(wsW, wsB, Y, acc2, acc3);
        k_final<float><<<(NPTS*CO)/256, 256, 0, stream>>>(wsW, Y, acc3, flagp, d_out);
    } else {
        unsigned short* Y = Vf + bigN;
        k_attn<unsigned short><<<NPTS/4, 64, 0, stream>>>(wsW, wsB, coords, key_idx, Qh, Kf, Vf, Y);
        k_outproj<unsigned short><<<NPTS/32, 256, 0, stream>>>(wsW, wsB, featv, flagp, Y, acc1);
        k_ffn<unsigned short><<<NPTS/32, 256, 0, stream>>>(wsW, wsB, Y, acc1, acc2);
        k_outl<unsigned short><<<NPTS/32, 256, 0, stream>>>(wsW, wsB, Y, acc2, acc3);
        k_final<unsigned short><<<(NPTS*CO)/256, 256, 0, stream>>>(wsW, Y, acc3, flagp, d_out);
    }
}

// Round 5
// 1063.235 us; speedup vs baseline: 1.8058x; 1.8058x over previous
//
#include <hip/hip_runtime.h>

#define NPTS 60000
#define C 128
#define K 32
#define FF 512
#define CO 128
#define H 8
#define DH 16
#define EPS 1e-5f

// ---- fp32 weight layout (float elements) ----
constexpr int OFF_INPROJ_W = 0;          // 384*128
constexpr int OFF_INPROJ_B = 49152;      // 384
constexpr int OFF_OUT_W    = 49536;      // 16384
constexpr int OFF_OUT_B    = 65920;      // 128
constexpr int OFF_QPOS_W   = 66048;      // 384
constexpr int OFF_QPOS_B   = 66432;      // 128
constexpr int OFF_KPOS_W   = 66560;      // 384
constexpr int OFF_KPOS_B   = 66944;      // 128
constexpr int OFF_N1G      = 67072;
constexpr int OFF_N1B      = 67200;
constexpr int OFF_N2G      = 67328;
constexpr int OFF_N2B      = 67456;
constexpr int OFF_LIN1_W   = 67584;      // 65536
constexpr int OFF_LIN1_B   = 133120;     // 512
constexpr int OFF_LIN2_W   = 133632;     // 65536
constexpr int OFF_LIN2_B   = 199168;     // 128
constexpr int OFF_OUTL_W   = 199296;     // 16384
constexpr int OFF_OUTL_B   = 215680;     // 128
constexpr int OFF_BOG      = 215808;
constexpr int OFF_BOB      = 215936;
constexpr int WTOTAL       = 216064;

// ---- bf16 weight copies (ushort elements within wsB) ----
constexpr int B_INPROJ = 0;        // 384x128 rows: wq(0..127) wk(128..255) wv(256..383)
constexpr int B_OUTW   = 49152;    // 128x128
constexpr int B_LIN1   = 65536;    // 512x128
constexpr int B_LIN2   = 131072;   // 128x512
constexpr int B_OUTL   = 196608;   // 128x128
constexpr int B_WKT    = 212992;   // 128x128: wkT[c][r] = wk[r][c]
constexpr size_t OFF_WB_BYTES  = 1587456;
constexpr size_t OFF_BIG_BYTES = 2046208;

typedef __attribute__((ext_vector_type(8))) short bfrag8;
typedef __attribute__((ext_vector_type(4))) float f32x4;

__device__ __forceinline__ float bf2f(unsigned short s) {
    return __uint_as_float(((unsigned)s) << 16);
}
__device__ __forceinline__ unsigned short f2bf(float f) {
    unsigned u = __float_as_uint(f);
    u += 0x7fffu + ((u >> 16) & 1u);
    return (unsigned short)(u >> 16);
}
__device__ __forceinline__ float ldE(const float* p, long i) { return p[i]; }
__device__ __forceinline__ float ldE(const unsigned short* p, long i) { return bf2f(p[i]); }
__device__ __forceinline__ void stE(float* p, long i, float v) { p[i] = v; }
__device__ __forceinline__ void stE(unsigned short* p, long i, float v) { p[i] = f2bf(v); }
__device__ __forceinline__ float ldF(const void* p, long i, int bf) {
    return bf ? bf2f(((const unsigned short*)p)[i]) : ((const float*)p)[i];
}
__device__ __forceinline__ bfrag8 ldfrag(const unsigned short* base, int stride, int lane, int k0) {
    return *(const bfrag8*)(base + (lane & 15) * stride + k0 + ((lane >> 4) << 3));
}

// ---- dtype probe ----
__global__ __launch_bounds__(256) void k_detect(const unsigned short* __restrict__ f,
                                                int* __restrict__ flag) {
    __shared__ int cnt_s;
    if (threadIdx.x == 0) cnt_s = 0;
    __syncthreads();
    int sane = 0;
    for (int j = 0; j < 16; ++j) {
        unsigned short u = f[threadIdx.x * 16 + j];
        int e = (u >> 7) & 255;
        sane += (u == 0 || (e >= 100 && e <= 142)) ? 1 : 0;
    }
    atomicAdd(&cnt_s, sane);
    __syncthreads();
    if (threadIdx.x == 0) *flag = (cnt_s >= 3686) ? 1 : 0;
}

struct WTab {
    const void* src[20];
    int beg[20];
    int end[20];
    int bo[20];
};

__global__ __launch_bounds__(256) void k_cvt_weights(WTab tab, float* __restrict__ ws,
                                                     unsigned short* __restrict__ wsB,
                                                     const int* __restrict__ flagp) {
    int bf = *flagp;
    int gid = blockIdx.x * 256 + threadIdx.x;
    #pragma unroll
    for (int j = 0; j < 20; ++j) {
        if (gid >= tab.beg[j] && gid < tab.end[j]) {
            int off = gid - tab.beg[j];
            float v;
            unsigned short raw;
            if (bf) { raw = ((const unsigned short*)tab.src[j])[off]; v = bf2f(raw); }
            else    { v = ((const float*)tab.src[j])[off]; raw = f2bf(v); }
            ws[gid] = v;
            if (tab.bo[j] >= 0) wsB[tab.bo[j] + off] = raw;
            if (j == 0 && off >= 16384 && off < 32768) {   // wk rows -> transposed copy
                int r = (off >> 7) - 128;
                int c = off & 127;
                wsB[B_WKT + c * C + r] = raw;
            }
        }
    }
}

// ---- fused coords + qpos + QKV projection (MFMA, bf16 outputs) ----
template <typename T>
__global__ __launch_bounds__(256) void k_proj(
    const float* __restrict__ wsW, const unsigned short* __restrict__ wsB,
    const void* __restrict__ featv, const int* __restrict__ flagp,
    const int* __restrict__ indices, float* __restrict__ coords,
    T* __restrict__ Qh, T* __restrict__ Kf, T* __restrict__ Vf)
{
    __shared__ __align__(16) unsigned short sxb[32][136];
    __shared__ __align__(16) unsigned short sqb[32][136];
    __shared__ float scd[32][4];
    int t = threadIdx.x;
    int row0 = blockIdx.x * 32;
    const int bf = *flagp;
    if (t < 96) {
        int r = t / 3, j = t - 3 * r;
        int n = row0 + r;
        int srci = (j == 0) ? 3 : (j == 1 ? 2 : 1);
        float vs = (j == 2) ? 0.2f : 0.1f;
        float mn = (j == 2) ? -3.0f : -40.0f;
        float v = ((float)indices[n * 4 + srci] + 0.5f) * vs + mn;
        scd[r][j] = v;
        coords[n * 3 + j] = v;
    }
    __syncthreads();
    const float* qpw = wsW + OFF_QPOS_W;
    const float* qpb = wsW + OFF_QPOS_B;
    for (int i = t; i < 32 * C; i += 256) {
        int r = i >> 7, c = i & 127;
        float x = ldF(featv, (long)row0 * C + i, bf);
        float a = qpb[c] + scd[r][0]*qpw[c*3] + scd[r][1]*qpw[c*3+1] + scd[r][2]*qpw[c*3+2];
        sxb[r][c] = f2bf(x);
        sqb[r][c] = f2bf(x + fmaxf(a, 0.0f));
    }
    __syncthreads();
    int lane = t & 63, w = t >> 6;
    int col = lane & 15, quad = lane >> 4;
    for (int tid = w; tid < 16; tid += 4) {
        int mt = tid & 1, nt = tid >> 1, n0 = nt * 16;
        f32x4 acc = {0.f, 0.f, 0.f, 0.f};
        const unsigned short* aB = &sqb[mt*16][0];
        const unsigned short* bB = wsB + B_INPROJ + n0 * C;
        #pragma unroll
        for (int kt = 0; kt < 4; ++kt) {
            bfrag8 a = ldfrag(aB, 136, lane, kt*32);
            bfrag8 b = ldfrag(bB, C, lane, kt*32);
            acc = __builtin_amdgcn_mfma_f32_16x16x32_bf16(a, b, acc, 0, 0, 0);
        }
        #pragma unroll
        for (int r = 0; r < 4; ++r) {
            int m = row0 + mt*16 + quad*4 + r;
            int n = n0 + col;
            stE(Qh, (long)m * C + n, acc[r] + wsW[OFF_INPROJ_B + n]);
        }
    }
    for (int tid = w; tid < 32; tid += 4) {
        int mt = tid & 1, nt = tid >> 1;
        int ng0 = 128 + nt * 16;
        f32x4 acc = {0.f, 0.f, 0.f, 0.f};
        const unsigned short* aB = &sxb[mt*16][0];
        const unsigned short* bB = wsB + B_INPROJ + ng0 * C;
        #pragma unroll
        for (int kt = 0; kt < 4; ++kt) {
            bfrag8 a = ldfrag(aB, 136, lane, kt*32);
            bfrag8 b = ldfrag(bB, C, lane, kt*32);
            acc = __builtin_amdgcn_mfma_f32_16x16x32_bf16(a, b, acc, 0, 0, 0);
        }
        #pragma unroll
        for (int r = 0; r < 4; ++r) {
            int m = row0 + mt*16 + quad*4 + r;
            int ng = ng0 + col;
            float v = acc[r] + wsW[OFF_INPROJ_B + ng];
            if (ng < 256) stE(Kf, (long)m * C + (ng - 128), v);
            else          stE(Vf, (long)m * C + (ng - 256), v);
        }
    }
}

// ---- attention: 2 waves per block, each wave owns one point ----
// R rows 0-15: masked qhA -> later pv rows 0-15; rows 16-31: qkt -> later pv rows 16-31.
// score = (qhA.Kf[g] + qkt.p) * 0.25 via one mfma chain (B-frags: gathered global Kf, LDS p).
template <typename T>
__global__ __launch_bounds__(128) void k_attn(
    const float* __restrict__ wsW, const unsigned short* __restrict__ wsB,
    const float* __restrict__ coords, const int* __restrict__ key_idx,
    const unsigned short* __restrict__ Qh, const unsigned short* __restrict__ Kf,
    const unsigned short* __restrict__ Vf, T* __restrict__ Y)
{
    __shared__ __align__(16) unsigned short P[2][32][136];
    __shared__ __align__(16) unsigned short R[2][32][136];
    __shared__ __align__(16) float SC[2][8][36];
    __shared__ __align__(16) float REL[2][32][4];
    __shared__ __align__(16) int   GS[2][32];
    __shared__ float CEN[2][4];

    int w = threadIdx.x >> 6;
    int l = threadIdx.x & 63;
    int n = blockIdx.x * 2 + w;
    int col = l & 15, quad = l >> 4;
    int c0 = 2 * l;

    const float* kpwp = wsW + OFF_KPOS_W;
    float kw00 = kpwp[c0*3],     kw01 = kpwp[c0*3+1],     kw02 = kpwp[c0*3+2];
    float kw10 = kpwp[c0*3+3],   kw11 = kpwp[c0*3+4],     kw12 = kpwp[c0*3+5];
    float kb0 = wsW[OFF_KPOS_B + c0], kb1 = wsW[OFF_KPOS_B + c0 + 1];
    const unsigned short* wkT = wsB + B_WKT;
    const unsigned short* wvp = wsB + B_INPROJ + 256 * C;

    // Ph0: gather indices + center
    if (l < 32) GS[w][l] = key_idx[n * K + l];
    if (l >= 32 && l < 35) CEN[w][l - 32] = coords[n * 3 + (l - 32)];
    __syncthreads();
    // Ph1: rel coords + zero qhA rows 0-7
    if (l < 32) {
        int gc = max(GS[w][l], 0);
        REL[w][l][0] = coords[gc*3+0] - CEN[w][0];
        REL[w][l][1] = coords[gc*3+1] - CEN[w][1];
        REL[w][l][2] = coords[gc*3+2] - CEN[w][2];
        REL[w][l][3] = 0.f;
    }
    {
        unsigned* rz = (unsigned*)&R[w][0][0];
        #pragma unroll
        for (int z = 0; z < 9; ++z) {
            int idx = l + z * 64;
            if (idx < 544) rz[idx] = 0;   // 8 rows * 136 u16
        }
    }
    __syncthreads();
    // Ph2: scatter qh into masked block-diag tile; build p[k][c] (lane owns c0,c0+1)
    {
        unsigned qv = ((const unsigned*)(Qh + (long)n * C))[l];
        *(unsigned*)&R[w][l >> 3][c0] = qv;
    }
    #pragma unroll 8
    for (int k = 0; k < K; ++k) {
        float4 rr = *(const float4*)&REL[w][k][0];
        float p0 = fmaxf(kb0 + rr.x*kw00 + rr.y*kw01 + rr.z*kw02, 0.f);
        float p1 = fmaxf(kb1 + rr.x*kw10 + rr.y*kw11 + rr.z*kw12, 0.f);
        *(unsigned*)&P[w][k][c0] = (unsigned)f2bf(p0) | ((unsigned)f2bf(p1) << 16);
    }
    __syncthreads();
    // Ph3: qkt[h][c] via masked-A mfma vs wkT (global B)
    bfrag8 aq[4];
    #pragma unroll
    for (int ks = 0; ks < 4; ++ks)
        aq[ks] = *(const bfrag8*)(&R[w][0][0] + col * 136 + ks * 32 + quad * 8);
    #pragma unroll
    for (int nt = 0; nt < 8; ++nt) {
        f32x4 d = {0.f, 0.f, 0.f, 0.f};
        #pragma unroll
        for (int ks = 0; ks < 4; ++ks) {
            bfrag8 b = *(const bfrag8*)(wkT + (nt * 16 + col) * C + ks * 32 + quad * 8);
            d = __builtin_amdgcn_mfma_f32_16x16x32_bf16(aq[ks], b, d, 0, 0, 0);
        }
        #pragma unroll
        for (int r = 0; r < 4; ++r)
            R[w][16 + quad * 4 + r][nt * 16 + col] = f2bf(d[r]);
    }
    __syncthreads();
    // Ph4: scores = qhA.Kf[g] (gathered global B-frags) + qkt.p (LDS B-frags), one chain
    bfrag8 ak[4];
    #pragma unroll
    for (int ks = 0; ks < 4; ++ks)
        ak[ks] = *(const bfrag8*)(&R[w][16][0] + col * 136 + ks * 32 + quad * 8);
    #pragma unroll
    for (int nt = 0; nt < 2; ++nt) {
        int g = GS[w][nt * 16 + col];
        const unsigned short* kf = Kf + (long)max(g, 0) * C;
        f32x4 acc = {0.f, 0.f, 0.f, 0.f};
        #pragma unroll
        for (int ks = 0; ks < 4; ++ks) {
            bfrag8 bk = *(const bfrag8*)(kf + ks * 32 + quad * 8);
            acc = __builtin_amdgcn_mfma_f32_16x16x32_bf16(aq[ks], bk, acc, 0, 0, 0);
        }
        #pragma unroll
        for (int ks = 0; ks < 4; ++ks) {
            bfrag8 bp = *(const bfrag8*)(&P[w][nt * 16 + col][0] + ks * 32 + quad * 8);
            acc = __builtin_amdgcn_mfma_f32_16x16x32_bf16(ak[ks], bp, acc, 0, 0, 0);
        }
        if (quad < 2) {
            #pragma unroll
            for (int r = 0; r < 4; ++r) {
                int h = quad * 4 + r, k = nt * 16 + col;
                SC[w][h][k] = (g < 0) ? -1e30f : acc[r] * 0.25f;
            }
        }
    }
    __syncthreads();
    // Ph5: softmax per h (8 lanes per h, 4 k each)
    {
        int h = l >> 3, sub = l & 7;
        float v0 = SC[w][h][sub],      v1 = SC[w][h][sub + 8];
        float v2 = SC[w][h][sub + 16], v3 = SC[w][h][sub + 24];
        float m = fmaxf(fmaxf(v0, v1), fmaxf(v2, v3));
        m = fmaxf(m, __shfl_xor(m, 1));
        m = fmaxf(m, __shfl_xor(m, 2));
        m = fmaxf(m, __shfl_xor(m, 4));
        float e0 = __expf(v0 - m), e1 = __expf(v1 - m), e2 = __expf(v2 - m), e3 = __expf(v3 - m);
        float s = e0 + e1 + e2 + e3;
        s += __shfl_xor(s, 1);
        s += __shfl_xor(s, 2);
        s += __shfl_xor(s, 4);
        float inv = 1.0f / s;
        SC[w][h][sub]      = e0 * inv;
        SC[w][h][sub + 8]  = e1 * inv;
        SC[w][h][sub + 16] = e2 * inv;
        SC[w][h][sub + 24] = e3 * inv;
    }
    __syncthreads();
    // Ph6: pv[k][c] = p_k . wv_c (full-M mfma), overwrite R rows 0-31
    {
        bfrag8 ap[2][4];
        #pragma unroll
        for (int mt = 0; mt < 2; ++mt)
            #pragma unroll
            for (int ks = 0; ks < 4; ++ks)
                ap[mt][ks] = *(const bfrag8*)(&P[w][mt * 16][0] + col * 136 + ks * 32 + quad * 8);
        #pragma unroll
        for (int nt = 0; nt < 8; ++nt) {
            f32x4 d0 = {0.f, 0.f, 0.f, 0.f}, d1 = {0.f, 0.f, 0.f, 0.f};
            #pragma unroll
            for (int ks = 0; ks < 4; ++ks) {
                bfrag8 b = *(const bfrag8*)(wvp + (nt * 16 + col) * C + ks * 32 + quad * 8);
                d0 = __builtin_amdgcn_mfma_f32_16x16x32_bf16(ap[0][ks], b, d0, 0, 0, 0);
                d1 = __builtin_amdgcn_mfma_f32_16x16x32_bf16(ap[1][ks], b, d1, 0, 0, 0);
            }
            #pragma unroll
            for (int r = 0; r < 4; ++r) {
                int c = nt * 16 + col;
                R[w][quad * 4 + r][c]      = f2bf(d0[r]);
                R[w][16 + quad * 4 + r][c] = f2bf(d1[r]);
            }
        }
    }
    __syncthreads();
    // Ph7: att[c] = sum_k attn[h_c][k] * (Vf[g_k][c] + pv[k][c]); lane owns c0, c0+1
    {
        int h = l >> 3;
        float a0 = 0.f, a1 = 0.f;
        #pragma unroll
        for (int k0 = 0; k0 < K; k0 += 4) {
            int4  g4  = *(const int4*)&GS[w][k0];
            float4 at4 = *(const float4*)&SC[w][h][k0];
            #pragma unroll
            for (int j = 0; j < 4; ++j) {
                int gc = max(((const int*)&g4)[j], 0);
                unsigned vv = *(const unsigned*)(Vf + (long)gc * C + c0);
                unsigned pp = *(const unsigned*)&R[w][k0 + j][c0];
                float at = ((const float*)&at4)[j];
                a0 += at * (bf2f((unsigned short)vv) + bf2f((unsigned short)pp));
                a1 += at * (bf2f((unsigned short)(vv >> 16)) + bf2f((unsigned short)(pp >> 16)));
            }
        }
        stE(Y, (long)n * C + c0, a0);
        stE(Y, (long)n * C + c0 + 1, a1);
    }
}

// ---- out-proj + residual + bn1 stats (MFMA) ----
template <typename T>
__global__ __launch_bounds__(256) void k_outproj(
    const float* __restrict__ wsW, const unsigned short* __restrict__ wsB,
    const void* __restrict__ featv, const int* __restrict__ flagp,
    T* __restrict__ Y, float* __restrict__ acc_s)
{
    __shared__ __align__(16) unsigned short sab[32][136];
    __shared__ float syf[32][132];
    int t = threadIdx.x;
    int row0 = blockIdx.x * 32;
    const int bf = *flagp;
    for (int i = t; i < 32 * C; i += 256)
        sab[i>>7][i&127] = f2bf(ldE(Y, (long)row0 * C + i));
    __syncthreads();
    int lane = t & 63, w = t >> 6;
    int col = lane & 15, quad = lane >> 4;
    for (int tid = w; tid < 16; tid += 4) {
        int mt = tid & 1, nt = tid >> 1, n0 = nt * 16;
        f32x4 acc = {0.f, 0.f, 0.f, 0.f};
        const unsigned short* aB = &sab[mt*16][0];
        const unsigned short* bB = wsB + B_OUTW + n0 * C;
        #pragma unroll
        for (int kt = 0; kt < 4; ++kt) {
            bfrag8 a = ldfrag(aB, 136, lane, kt*32);
            bfrag8 b = ldfrag(bB, C, lane, kt*32);
            acc = __builtin_amdgcn_mfma_f32_16x16x32_bf16(a, b, acc, 0, 0, 0);
        }
        #pragma unroll
        for (int r = 0; r < 4; ++r) {
            int m = mt*16 + quad*4 + r;
            int n = n0 + col;
            syf[m][n] = acc[r] + wsW[OFF_OUT_B + n] + ldF(featv, (long)(row0+m)*C + n, bf);
        }
    }
    __syncthreads();
    for (int i = t; i < 32 * C; i += 256)
        stE(Y, (long)row0 * C + i, syf[i>>7][i&127]);
    if (t < C) {
        float s = 0.f, sq = 0.f;
        for (int r = 0; r < 32; ++r) { float v = syf[r][t]; s += v; sq += v*v; }
        atomicAdd(&acc_s[t], s);
        atomicAdd(&acc_s[C + t], sq);
    }
}

// ---- bn1 + FFN + residual + bn2 stats (MFMA) ----
template <typename T>
__global__ __launch_bounds__(256) void k_ffn(
    const float* __restrict__ wsW, const unsigned short* __restrict__ wsB,
    T* __restrict__ Y, const float* __restrict__ acc1, float* __restrict__ acc2)
{
    __shared__ __align__(16) unsigned short sxb[32][136];
    __shared__ __align__(16) unsigned short sh[32][520];
    __shared__ float nsc[C], nsh[C];
    float (*syf)[132] = (float(*)[132])sh;
    int t = threadIdx.x;
    int row0 = blockIdx.x * 32;
    if (t < C) {
        float m = acc1[t] * (1.0f/NPTS);
        float v = acc1[C+t] * (1.0f/NPTS) - m*m;
        float rs = rsqrtf(v + EPS);
        float sc = rs * wsW[OFF_N1G + t];
        nsc[t] = sc;
        nsh[t] = wsW[OFF_N1B + t] - m * sc;
    }
    __syncthreads();
    for (int i = t; i < 32 * C; i += 256) {
        int c = i & 127;
        sxb[i>>7][c] = f2bf(ldE(Y, (long)row0 * C + i) * nsc[c] + nsh[c]);
    }
    __syncthreads();
    int lane = t & 63, w = t >> 6;
    int col = lane & 15, quad = lane >> 4;
    for (int tid = w; tid < 64; tid += 4) {
        int mt = tid & 1, nt = tid >> 1, n0 = nt * 16;
        f32x4 acc = {0.f, 0.f, 0.f, 0.f};
        const unsigned short* aB = &sxb[mt*16][0];
        const unsigned short* bB = wsB + B_LIN1 + n0 * C;
        #pragma unroll
        for (int kt = 0; kt < 4; ++kt) {
            bfrag8 a = ldfrag(aB, 136, lane, kt*32);
            bfrag8 b = ldfrag(bB, C, lane, kt*32);
            acc = __builtin_amdgcn_mfma_f32_16x16x32_bf16(a, b, acc, 0, 0, 0);
        }
        #pragma unroll
        for (int r = 0; r < 4; ++r) {
            int m = mt*16 + quad*4 + r;
            int n = n0 + col;
            sh[m][n] = f2bf(fmaxf(acc[r] + wsW[OFF_LIN1_B + n], 0.f));
        }
    }
    __syncthreads();
    f32x4 accT[4];
    #pragma unroll
    for (int i = 0; i < 4; ++i) {
        int tid = w + 4*i;
        int mt = tid & 1, nt = tid >> 1, n0 = nt * 16;
        f32x4 acc = {0.f, 0.f, 0.f, 0.f};
        const unsigned short* aB = &sh[mt*16][0];
        const unsigned short* bB = wsB + B_LIN2 + n0 * FF;
        #pragma unroll
        for (int kt = 0; kt < 16; ++kt) {
            bfrag8 a = ldfrag(aB, 520, lane, kt*32);
            bfrag8 b = ldfrag(bB, FF, lane, kt*32);
            acc = __builtin_amdgcn_mfma_f32_16x16x32_bf16(a, b, acc, 0, 0, 0);
        }
        accT[i] = acc;
    }
    __syncthreads();
    #pragma unroll
    for (int i = 0; i < 4; ++i) {
        int tid = w + 4*i;
        int mt = tid & 1, nt = tid >> 1, n0 = nt * 16;
        #pragma unroll
        for (int r = 0; r < 4; ++r) {
            int m = mt*16 + quad*4 + r;
            int n = n0 + col;
            syf[m][n] = accT[i][r] + wsW[OFF_LIN2_B + n] + bf2f(sxb[m][n]);
        }
    }
    __syncthreads();
    for (int i = t; i < 32 * C; i += 256)
        stE(Y, (long)row0 * C + i, syf[i>>7][i&127]);
    if (t < C) {
        float s = 0.f, sq = 0.f;
        for (int r = 0; r < 32; ++r) { float v = syf[r][t]; s += v; sq += v*v; }
        atomicAdd(&acc2[t], s);
        atomicAdd(&acc2[C+t], sq);
    }
}

// ---- bn2 + output linear + bn3 stats (MFMA) ----
template <typename T>
__global__ __launch_bounds__(256) void k_outl(
    const float* __restrict__ wsW, const unsigned short* __restrict__ wsB,
    T* __restrict__ Y, const float* __restrict__ acc2, float* __restrict__ acc3)
{
    __shared__ __align__(16) unsigned short sxb[32][136];
    __shared__ float syf[32][132];
    __shared__ float nsc[C], nsh[C];
    int t = threadIdx.x;
    int row0 = blockIdx.x * 32;
    if (t < C) {
        float m = acc2[t] * (1.0f/NPTS);
        float v = acc2[C+t] * (1.0f/NPTS) - m*m;
        float rs = rsqrtf(v + EPS);
        float sc = rs * wsW[OFF_N2G + t];
        nsc[t] = sc;
        nsh[t] = wsW[OFF_N2B + t] - m * sc;
    }
    __syncthreads();
    for (int i = t; i < 32 * C; i += 256) {
        int c = i & 127;
        sxb[i>>7][c] = f2bf(ldE(Y, (long)row0 * C + i) * nsc[c] + nsh[c]);
    }
    __syncthreads();
    int lane = t & 63, w = t >> 6;
    int col = lane & 15, quad = lane >> 4;
    for (int tid = w; tid < 16; tid += 4) {
        int mt = tid & 1, nt = tid >> 1, n0 = nt * 16;
        f32x4 acc = {0.f, 0.f, 0.f, 0.f};
        const unsigned short* aB = &sxb[mt*16][0];
        const unsigned short* bB = wsB + B_OUTL + n0 * C;
        #pragma unroll
        for (int kt = 0; kt < 4; ++kt) {
            bfrag8 a = ldfrag(aB, 136, lane, kt*32);
            bfrag8 b = ldfrag(bB, C, lane, kt*32);
            acc = __builtin_amdgcn_mfma_f32_16x16x32_bf16(a, b, acc, 0, 0, 0);
        }
        #pragma unroll
        for (int r = 0; r < 4; ++r) {
            int m = mt*16 + quad*4 + r;
            int n = n0 + col;
            syf[m][n] = acc[r] + wsW[OFF_OUTL_B + n];
        }
    }
    __syncthreads();
    for (int i = t; i < 32 * CO; i += 256)
        stE(Y, (long)row0 * CO + i, syf[i>>7][i&127]);
    if (t < CO) {
        float s = 0.f, sq = 0.f;
        for (int r = 0; r < 32; ++r) { float v = syf[r][t]; s += v; sq += v*v; }
        atomicAdd(&acc3[t], s);
        atomicAdd(&acc3[CO+t], sq);
    }
}

// ---- final BN + relu -> output ----
template <typename T>
__global__ __launch_bounds__(256) void k_final(
    const float* __restrict__ wsW, const T* __restrict__ Y,
    const float* __restrict__ acc3, const int* __restrict__ flagp,
    void* __restrict__ out)
{
    long i = (long)blockIdx.x * 256 + threadIdx.x;
    int c = (int)(i & (CO-1));
    float m = acc3[c] * (1.0f/NPTS);
    float v = acc3[CO+c] * (1.0f/NPTS) - m*m;
    float rs = rsqrtf(v + EPS);
    float y = (ldE(Y, i) - m) * rs * wsW[OFF_BOG + c] + wsW[OFF_BOB + c];
    y = fmaxf(y, 0.f);
    if (*flagp) ((unsigned short*)out)[i] = f2bf(y);
    else        ((float*)out)[i] = y;
}

extern "C" void kernel_launch(void* const* d_in, const int* in_sizes, int n_in,
                              void* d_out, int out_size, void* d_ws, size_t ws_size,
                              hipStream_t stream)
{
    char* base = (char*)d_ws;
    float* wsW = (float*)base;
    float* acc1 = wsW + WTOTAL;
    float* acc2 = acc1 + 256;
    float* acc3 = acc2 + 256;
    int* flagp = (int*)(wsW + WTOTAL + 768);
    float* coords = wsW + WTOTAL + 776;
    unsigned short* wsB = (unsigned short*)(base + OFF_WB_BYTES);

    const void* featv = d_in[0];
    const int* indices = (const int*)d_in[1];
    const int* key_idx = (const int*)d_in[2];

    hipMemsetAsync(acc1, 0, 768 * sizeof(float), stream);
    k_detect<<<1, 256, 0, stream>>>((const unsigned short*)d_in[0], flagp);

    static const int cnt[20] = {49152,384,16384,128,384,128,384,128,128,128,
                                128,128,65536,512,65536,128,16384,128,128,128};
    static const int bofs[20] = {B_INPROJ,-1,B_OUTW,-1,-1,-1,-1,-1,-1,-1,
                                 -1,-1,B_LIN1,-1,B_LIN2,-1,B_OUTL,-1,-1,-1};
    WTab tab;
    int off = 0;
    for (int j = 0; j < 20; ++j) {
        tab.src[j] = d_in[3 + j];
        tab.beg[j] = off;
        tab.end[j] = off + cnt[j];
        tab.bo[j] = bofs[j];
        off += cnt[j];
    }
    k_cvt_weights<<<WTOTAL/256, 256, 0, stream>>>(tab, wsW, wsB, flagp);

    size_t bigN = (size_t)NPTS * C;
    bool f32mode = (ws_size >= OFF_BIG_BYTES + 3 * bigN * 2 + bigN * 4);

    unsigned short* Qh = (unsigned short*)(base + OFF_BIG_BYTES);
    unsigned short* Kf = Qh + bigN;
    unsigned short* Vf = Kf + bigN;

    k_proj<unsigned short><<<NPTS/32, 256, 0, stream>>>(wsW, wsB, featv, flagp, indices, coords, Qh, Kf, Vf);

    if (f32mode) {
        float* Y = (float*)(Vf + bigN);
        k_attn<float><<<NPTS/2, 128, 0, stream>>>(wsW, wsB, coords, key_idx, Qh, Kf, Vf, Y);
        k_outproj<float><<<NPTS/32, 256, 0, stream>>>(wsW, wsB, featv, flagp, Y, acc1);
        k_ffn<float><<<NPTS/32, 256, 0, stream>>>(wsW, wsB, Y, acc1, acc2);
        k_outl<float><<<NPTS/32, 256, 0, stream>>>(wsW, wsB, Y, acc2, acc3);
        k_final<float><<<(NPTS*CO)/256, 256, 0, stream>>>(wsW, Y, acc3, flagp, d_out);
    } else {
        unsigned short* Y = Vf + bigN;
        k_attn<unsigned short><<<NPTS/2, 128, 0, stream>>>(wsW, wsB, coords, key_idx, Qh, Kf, Vf, Y);
        k_outproj<unsigned short><<<NPTS/32, 256, 0, stream>>>(wsW, wsB, featv, flagp, Y, acc1);
        k_ffn<unsigned short><<<NPTS/32, 256, 0, stream>>>(wsW, wsB, Y, acc1, acc2);
        k_outl<unsigned short><<<NPTS/32, 256, 0, stream>>>(wsW, wsB, Y, acc2, acc3);
        k_final<unsigned short><<<(NPTS*CO)/256, 256, 0, stream>>>(wsW, Y, acc3, flagp, d_out);
    }
}

// Round 6
// 1005.780 us; speedup vs baseline: 1.9089x; 1.0571x over previous
//
#include <hip/hip_runtime.h>

#define NPTS 60000
#define C 128
#define K 32
#define FF 512
#define CO 128
#define H 8
#define DH 16
#define EPS 1e-5f

// ---- fp32 weight layout (float elements) ----
constexpr int OFF_INPROJ_W = 0;          // 384*128
constexpr int OFF_INPROJ_B = 49152;      // 384
constexpr int OFF_OUT_W    = 49536;      // 16384
constexpr int OFF_OUT_B    = 65920;      // 128
constexpr int OFF_QPOS_W   = 66048;      // 384
constexpr int OFF_QPOS_B   = 66432;      // 128
constexpr int OFF_KPOS_W   = 66560;      // 384
constexpr int OFF_KPOS_B   = 66944;      // 128
constexpr int OFF_N1G      = 67072;
constexpr int OFF_N1B      = 67200;
constexpr int OFF_N2G      = 67328;
constexpr int OFF_N2B      = 67456;
constexpr int OFF_LIN1_W   = 67584;      // 65536
constexpr int OFF_LIN1_B   = 133120;     // 512
constexpr int OFF_LIN2_W   = 133632;     // 65536
constexpr int OFF_LIN2_B   = 199168;     // 128
constexpr int OFF_OUTL_W   = 199296;     // 16384
constexpr int OFF_OUTL_B   = 215680;     // 128
constexpr int OFF_BOG      = 215808;
constexpr int OFF_BOB      = 215936;
constexpr int WTOTAL       = 216064;

// ---- bf16 weight copies (ushort elements within wsB) ----
constexpr int B_INPROJ = 0;        // 384x128 rows: wq(0..127) wk(128..255) wv(256..383)
constexpr int B_OUTW   = 49152;    // 128x128
constexpr int B_LIN1   = 65536;    // 512x128
constexpr int B_LIN2   = 131072;   // 128x512
constexpr int B_OUTL   = 196608;   // 128x128
constexpr int B_WKT    = 212992;   // 128x128: wkT[c][r] = wk[r][c]
constexpr size_t OFF_WB_BYTES  = 1587456;
constexpr size_t OFF_BIG_BYTES = 2046208;

typedef __attribute__((ext_vector_type(8))) short bfrag8;
typedef __attribute__((ext_vector_type(4))) float f32x4;

__device__ __forceinline__ float bf2f(unsigned short s) {
    return __uint_as_float(((unsigned)s) << 16);
}
__device__ __forceinline__ unsigned short f2bf(float f) {
    unsigned u = __float_as_uint(f);
    u += 0x7fffu + ((u >> 16) & 1u);
    return (unsigned short)(u >> 16);
}
__device__ __forceinline__ float ldE(const float* p, long i) { return p[i]; }
__device__ __forceinline__ float ldE(const unsigned short* p, long i) { return bf2f(p[i]); }
__device__ __forceinline__ void stE(float* p, long i, float v) { p[i] = v; }
__device__ __forceinline__ void stE(unsigned short* p, long i, float v) { p[i] = f2bf(v); }
__device__ __forceinline__ float ldF(const void* p, long i, int bf) {
    return bf ? bf2f(((const unsigned short*)p)[i]) : ((const float*)p)[i];
}
__device__ __forceinline__ bfrag8 ldfrag(const unsigned short* base, int stride, int lane, int k0) {
    return *(const bfrag8*)(base + (lane & 15) * stride + k0 + ((lane >> 4) << 3));
}

// ---- dtype probe ----
__global__ __launch_bounds__(256) void k_detect(const unsigned short* __restrict__ f,
                                                int* __restrict__ flag) {
    __shared__ int cnt_s;
    if (threadIdx.x == 0) cnt_s = 0;
    __syncthreads();
    int sane = 0;
    for (int j = 0; j < 16; ++j) {
        unsigned short u = f[threadIdx.x * 16 + j];
        int e = (u >> 7) & 255;
        sane += (u == 0 || (e >= 100 && e <= 142)) ? 1 : 0;
    }
    atomicAdd(&cnt_s, sane);
    __syncthreads();
    if (threadIdx.x == 0) *flag = (cnt_s >= 3686) ? 1 : 0;
}

struct WTab {
    const void* src[20];
    int beg[20];
    int end[20];
    int bo[20];
};

__global__ __launch_bounds__(256) void k_cvt_weights(WTab tab, float* __restrict__ ws,
                                                     unsigned short* __restrict__ wsB,
                                                     const int* __restrict__ flagp) {
    int bf = *flagp;
    int gid = blockIdx.x * 256 + threadIdx.x;
    #pragma unroll
    for (int j = 0; j < 20; ++j) {
        if (gid >= tab.beg[j] && gid < tab.end[j]) {
            int off = gid - tab.beg[j];
            float v;
            unsigned short raw;
            if (bf) { raw = ((const unsigned short*)tab.src[j])[off]; v = bf2f(raw); }
            else    { v = ((const float*)tab.src[j])[off]; raw = f2bf(v); }
            ws[gid] = v;
            if (tab.bo[j] >= 0) wsB[tab.bo[j] + off] = raw;
            if (j == 0 && off >= 16384 && off < 32768) {   // wk rows -> transposed copy
                int r = (off >> 7) - 128;
                int c = off & 127;
                wsB[B_WKT + c * C + r] = raw;
            }
        }
    }
}

// ---- fused coords + qpos + QKV projection (MFMA, bf16 outputs) ----
template <typename T>
__global__ __launch_bounds__(256) void k_proj(
    const float* __restrict__ wsW, const unsigned short* __restrict__ wsB,
    const void* __restrict__ featv, const int* __restrict__ flagp,
    const int* __restrict__ indices, float* __restrict__ coords,
    T* __restrict__ Qh, T* __restrict__ Kf, T* __restrict__ Vf)
{
    __shared__ __align__(16) unsigned short sxb[32][136];
    __shared__ __align__(16) unsigned short sqb[32][136];
    __shared__ float scd[32][4];
    int t = threadIdx.x;
    int row0 = blockIdx.x * 32;
    const int bf = *flagp;
    if (t < 96) {
        int r = t / 3, j = t - 3 * r;
        int n = row0 + r;
        int srci = (j == 0) ? 3 : (j == 1 ? 2 : 1);
        float vs = (j == 2) ? 0.2f : 0.1f;
        float mn = (j == 2) ? -3.0f : -40.0f;
        float v = ((float)indices[n * 4 + srci] + 0.5f) * vs + mn;
        scd[r][j] = v;
        coords[n * 3 + j] = v;
    }
    __syncthreads();
    const float* qpw = wsW + OFF_QPOS_W;
    const float* qpb = wsW + OFF_QPOS_B;
    for (int i = t; i < 32 * C; i += 256) {
        int r = i >> 7, c = i & 127;
        float x = ldF(featv, (long)row0 * C + i, bf);
        float a = qpb[c] + scd[r][0]*qpw[c*3] + scd[r][1]*qpw[c*3+1] + scd[r][2]*qpw[c*3+2];
        sxb[r][c] = f2bf(x);
        sqb[r][c] = f2bf(x + fmaxf(a, 0.0f));
    }
    __syncthreads();
    int lane = t & 63, w = t >> 6;
    int col = lane & 15, quad = lane >> 4;
    for (int tid = w; tid < 16; tid += 4) {
        int mt = tid & 1, nt = tid >> 1, n0 = nt * 16;
        f32x4 acc = {0.f, 0.f, 0.f, 0.f};
        const unsigned short* aB = &sqb[mt*16][0];
        const unsigned short* bB = wsB + B_INPROJ + n0 * C;
        #pragma unroll
        for (int kt = 0; kt < 4; ++kt) {
            bfrag8 a = ldfrag(aB, 136, lane, kt*32);
            bfrag8 b = ldfrag(bB, C, lane, kt*32);
            acc = __builtin_amdgcn_mfma_f32_16x16x32_bf16(a, b, acc, 0, 0, 0);
        }
        #pragma unroll
        for (int r = 0; r < 4; ++r) {
            int m = row0 + mt*16 + quad*4 + r;
            int n = n0 + col;
            stE(Qh, (long)m * C + n, acc[r] + wsW[OFF_INPROJ_B + n]);
        }
    }
    for (int tid = w; tid < 32; tid += 4) {
        int mt = tid & 1, nt = tid >> 1;
        int ng0 = 128 + nt * 16;
        f32x4 acc = {0.f, 0.f, 0.f, 0.f};
        const unsigned short* aB = &sxb[mt*16][0];
        const unsigned short* bB = wsB + B_INPROJ + ng0 * C;
        #pragma unroll
        for (int kt = 0; kt < 4; ++kt) {
            bfrag8 a = ldfrag(aB, 136, lane, kt*32);
            bfrag8 b = ldfrag(bB, C, lane, kt*32);
            acc = __builtin_amdgcn_mfma_f32_16x16x32_bf16(a, b, acc, 0, 0, 0);
        }
        #pragma unroll
        for (int r = 0; r < 4; ++r) {
            int m = row0 + mt*16 + quad*4 + r;
            int ng = ng0 + col;
            float v = acc[r] + wsW[OFF_INPROJ_B + ng];
            if (ng < 256) stE(Kf, (long)m * C + (ng - 128), v);
            else          stE(Vf, (long)m * C + (ng - 256), v);
        }
    }
}

// ---- attention: ONE wave per block, one point per wave ----
// Single-wave workgroup (launch_bounds 64): s_barrier is elided, __syncthreads
// lowers to waitcnt only -> loads stay in flight across phases, waves decoupled.
// R rows 0-15: masked qhA (A-frags to regs) -> overwritten by qkt D; rows 16-31: qkt
// ... wait: layout: rows 0-15 qhA, rows 16-31 qkt, then pv overwrites rows 0-31.
template <typename T>
__global__ __launch_bounds__(64) void k_attn(
    const float* __restrict__ wsW, const unsigned short* __restrict__ wsB,
    const float* __restrict__ coords, const int* __restrict__ key_idx,
    const unsigned short* __restrict__ Qh, const unsigned short* __restrict__ Kf,
    const unsigned short* __restrict__ Vf, T* __restrict__ Y)
{
    __shared__ __align__(16) unsigned short P[32][136];
    __shared__ __align__(16) unsigned short R[32][136];
    __shared__ __align__(16) float SC[8][36];
    __shared__ __align__(16) float REL[32][4];
    __shared__ __align__(16) int   GS[32];

    int l = threadIdx.x;
    int n = blockIdx.x;
    int col = l & 15, quad = l >> 4;
    int c0 = 2 * l;

    const float* kpwp = wsW + OFF_KPOS_W;
    float kw00 = kpwp[c0*3],   kw01 = kpwp[c0*3+1], kw02 = kpwp[c0*3+2];
    float kw10 = kpwp[c0*3+3], kw11 = kpwp[c0*3+4], kw12 = kpwp[c0*3+5];
    float kb0 = wsW[OFF_KPOS_B + c0], kb1 = wsW[OFF_KPOS_B + c0 + 1];
    const unsigned short* wkT = wsB + B_WKT;
    const unsigned short* wvp = wsB + B_INPROJ + 256 * C;

    // Ph0: key indices (LDS), center (uniform loads), qh (coalesced)
    if (l < 32) GS[l] = key_idx[n * K + l];
    float cenx = coords[n*3+0], ceny = coords[n*3+1], cenz = coords[n*3+2];
    unsigned qv = ((const unsigned*)(Qh + (long)n * C))[l];
    __syncthreads();

    // Prefetch gathered Kf score fragments (addresses depend only on GS)
    bfrag8 bk[2][4];
    #pragma unroll
    for (int nt = 0; nt < 2; ++nt) {
        int g = GS[nt * 16 + col];
        const unsigned short* kf = Kf + (long)max(g, 0) * C;
        #pragma unroll
        for (int ks = 0; ks < 4; ++ks)
            bk[nt][ks] = *(const bfrag8*)(kf + ks * 32 + quad * 8);
    }

    // Ph1: rel coords; zero qhA rows 0-7
    if (l < 32) {
        int gc = max(GS[l], 0);
        REL[l][0] = coords[gc*3+0] - cenx;
        REL[l][1] = coords[gc*3+1] - ceny;
        REL[l][2] = coords[gc*3+2] - cenz;
        REL[l][3] = 0.f;
    }
    {
        unsigned* rz = (unsigned*)&R[0][0];
        #pragma unroll
        for (int z = 0; z < 9; ++z) {
            int idx = l + z * 64;
            if (idx < 544) rz[idx] = 0;   // rows 0-7 incl padding
        }
    }
    __syncthreads();
    // Ph2: scatter qh into block-diag qhA rows 0-7; build p[k][c]
    *(unsigned*)&R[l >> 3][c0] = qv;
    #pragma unroll 8
    for (int k = 0; k < K; ++k) {
        float4 rr = *(const float4*)&REL[k][0];
        float p0 = fmaxf(kb0 + rr.x*kw00 + rr.y*kw01 + rr.z*kw02, 0.f);
        float p1 = fmaxf(kb1 + rr.x*kw10 + rr.y*kw11 + rr.z*kw12, 0.f);
        *(unsigned*)&P[k][c0] = (unsigned)f2bf(p0) | ((unsigned)f2bf(p1) << 16);
    }
    __syncthreads();
    // Ph3: qkt via masked-A mfma vs wkT (global B); aq first to regs, D -> rows 16-31
    bfrag8 aq[4];
    #pragma unroll
    for (int ks = 0; ks < 4; ++ks)
        aq[ks] = *(const bfrag8*)(&R[0][0] + col * 136 + ks * 32 + quad * 8);
    #pragma unroll
    for (int nt = 0; nt < 8; ++nt) {
        f32x4 d = {0.f, 0.f, 0.f, 0.f};
        #pragma unroll
        for (int ks = 0; ks < 4; ++ks) {
            bfrag8 b = *(const bfrag8*)(wkT + (nt * 16 + col) * C + ks * 32 + quad * 8);
            d = __builtin_amdgcn_mfma_f32_16x16x32_bf16(aq[ks], b, d, 0, 0, 0);
        }
        #pragma unroll
        for (int r = 0; r < 4; ++r)
            R[16 + quad * 4 + r][nt * 16 + col] = f2bf(d[r]);
    }
    __syncthreads();
    // Ph4: scores = qhA.Kf[g] (prefetched regs) + qkt.p (LDS B), one chain
    bfrag8 ak[4];
    #pragma unroll
    for (int ks = 0; ks < 4; ++ks)
        ak[ks] = *(const bfrag8*)(&R[16][0] + col * 136 + ks * 32 + quad * 8);
    #pragma unroll
    for (int nt = 0; nt < 2; ++nt) {
        int g = GS[nt * 16 + col];
        f32x4 acc = {0.f, 0.f, 0.f, 0.f};
        #pragma unroll
        for (int ks = 0; ks < 4; ++ks)
            acc = __builtin_amdgcn_mfma_f32_16x16x32_bf16(aq[ks], bk[nt][ks], acc, 0, 0, 0);
        #pragma unroll
        for (int ks = 0; ks < 4; ++ks) {
            bfrag8 bp = *(const bfrag8*)(&P[nt * 16 + col][0] + ks * 32 + quad * 8);
            acc = __builtin_amdgcn_mfma_f32_16x16x32_bf16(ak[ks], bp, acc, 0, 0, 0);
        }
        if (quad < 2) {
            #pragma unroll
            for (int r = 0; r < 4; ++r) {
                int h = quad * 4 + r, k = nt * 16 + col;
                SC[h][k] = (g < 0) ? -1e30f : acc[r] * 0.25f;
            }
        }
    }
    __syncthreads();
    // Ph5: softmax per h (8 lanes per h, 4 k each)
    {
        int h = l >> 3, sub = l & 7;
        float v0 = SC[h][sub],      v1 = SC[h][sub + 8];
        float v2 = SC[h][sub + 16], v3 = SC[h][sub + 24];
        float m = fmaxf(fmaxf(v0, v1), fmaxf(v2, v3));
        m = fmaxf(m, __shfl_xor(m, 1));
        m = fmaxf(m, __shfl_xor(m, 2));
        m = fmaxf(m, __shfl_xor(m, 4));
        float e0 = __expf(v0 - m), e1 = __expf(v1 - m), e2 = __expf(v2 - m), e3 = __expf(v3 - m);
        float s = e0 + e1 + e2 + e3;
        s += __shfl_xor(s, 1);
        s += __shfl_xor(s, 2);
        s += __shfl_xor(s, 4);
        float inv = 1.0f / s;
        SC[h][sub]      = e0 * inv;
        SC[h][sub + 8]  = e1 * inv;
        SC[h][sub + 16] = e2 * inv;
        SC[h][sub + 24] = e3 * inv;
    }
    __syncthreads();
    // Ph6: pv[k][c] = p_k . wv_c, overwrite R rows 0-31
    {
        bfrag8 ap[2][4];
        #pragma unroll
        for (int mt = 0; mt < 2; ++mt)
            #pragma unroll
            for (int ks = 0; ks < 4; ++ks)
                ap[mt][ks] = *(const bfrag8*)(&P[mt * 16][0] + col * 136 + ks * 32 + quad * 8);
        #pragma unroll
        for (int nt = 0; nt < 8; ++nt) {
            f32x4 d0 = {0.f, 0.f, 0.f, 0.f}, d1 = {0.f, 0.f, 0.f, 0.f};
            #pragma unroll
            for (int ks = 0; ks < 4; ++ks) {
                bfrag8 b = *(const bfrag8*)(wvp + (nt * 16 + col) * C + ks * 32 + quad * 8);
                d0 = __builtin_amdgcn_mfma_f32_16x16x32_bf16(ap[0][ks], b, d0, 0, 0, 0);
                d1 = __builtin_amdgcn_mfma_f32_16x16x32_bf16(ap[1][ks], b, d1, 0, 0, 0);
            }
            #pragma unroll
            for (int r = 0; r < 4; ++r) {
                int c = nt * 16 + col;
                R[quad * 4 + r][c]      = f2bf(d0[r]);
                R[16 + quad * 4 + r][c] = f2bf(d1[r]);
            }
        }
    }
    __syncthreads();
    // Ph7: att[c] = sum_k attn[h_c][k] * (Vf[g_k][c] + pv[k][c]); lane owns c0,c0+1
    {
        int h = l >> 3;
        float a0 = 0.f, a1 = 0.f;
        #pragma unroll
        for (int k0 = 0; k0 < K; k0 += 4) {
            int4  g4  = *(const int4*)&GS[k0];
            float4 at4 = *(const float4*)&SC[h][k0];
            #pragma unroll
            for (int j = 0; j < 4; ++j) {
                int gc = max(((const int*)&g4)[j], 0);
                unsigned vv = *(const unsigned*)(Vf + (long)gc * C + c0);
                unsigned pp = *(const unsigned*)&R[k0 + j][c0];
                float at = ((const float*)&at4)[j];
                a0 += at * (bf2f((unsigned short)vv) + bf2f((unsigned short)pp));
                a1 += at * (bf2f((unsigned short)(vv >> 16)) + bf2f((unsigned short)(pp >> 16)));
            }
        }
        stE(Y, (long)n * C + c0, a0);
        stE(Y, (long)n * C + c0 + 1, a1);
    }
}

// ---- out-proj + residual + bn1 stats (MFMA) ----
template <typename T>
__global__ __launch_bounds__(256) void k_outproj(
    const float* __restrict__ wsW, const unsigned short* __restrict__ wsB,
    const void* __restrict__ featv, const int* __restrict__ flagp,
    T* __restrict__ Y, float* __restrict__ acc_s)
{
    __shared__ __align__(16) unsigned short sab[32][136];
    __shared__ float syf[32][132];
    int t = threadIdx.x;
    int row0 = blockIdx.x * 32;
    const int bf = *flagp;
    for (int i = t; i < 32 * C; i += 256)
        sab[i>>7][i&127] = f2bf(ldE(Y, (long)row0 * C + i));
    __syncthreads();
    int lane = t & 63, w = t >> 6;
    int col = lane & 15, quad = lane >> 4;
    for (int tid = w; tid < 16; tid += 4) {
        int mt = tid & 1, nt = tid >> 1, n0 = nt * 16;
        f32x4 acc = {0.f, 0.f, 0.f, 0.f};
        const unsigned short* aB = &sab[mt*16][0];
        const unsigned short* bB = wsB + B_OUTW + n0 * C;
        #pragma unroll
        for (int kt = 0; kt < 4; ++kt) {
            bfrag8 a = ldfrag(aB, 136, lane, kt*32);
            bfrag8 b = ldfrag(bB, C, lane, kt*32);
            acc = __builtin_amdgcn_mfma_f32_16x16x32_bf16(a, b, acc, 0, 0, 0);
        }
        #pragma unroll
        for (int r = 0; r < 4; ++r) {
            int m = mt*16 + quad*4 + r;
            int n = n0 + col;
            syf[m][n] = acc[r] + wsW[OFF_OUT_B + n] + ldF(featv, (long)(row0+m)*C + n, bf);
        }
    }
    __syncthreads();
    for (int i = t; i < 32 * C; i += 256)
        stE(Y, (long)row0 * C + i, syf[i>>7][i&127]);
    if (t < C) {
        float s = 0.f, sq = 0.f;
        for (int r = 0; r < 32; ++r) { float v = syf[r][t]; s += v; sq += v*v; }
        atomicAdd(&acc_s[t], s);
        atomicAdd(&acc_s[C + t], sq);
    }
}

// ---- bn1 + FFN + residual + bn2 stats (MFMA) ----
template <typename T>
__global__ __launch_bounds__(256) void k_ffn(
    const float* __restrict__ wsW, const unsigned short* __restrict__ wsB,
    T* __restrict__ Y, const float* __restrict__ acc1, float* __restrict__ acc2)
{
    __shared__ __align__(16) unsigned short sxb[32][136];
    __shared__ __align__(16) unsigned short sh[32][520];
    __shared__ float nsc[C], nsh[C];
    float (*syf)[132] = (float(*)[132])sh;
    int t = threadIdx.x;
    int row0 = blockIdx.x * 32;
    if (t < C) {
        float m = acc1[t] * (1.0f/NPTS);
        float v = acc1[C+t] * (1.0f/NPTS) - m*m;
        float rs = rsqrtf(v + EPS);
        float sc = rs * wsW[OFF_N1G + t];
        nsc[t] = sc;
        nsh[t] = wsW[OFF_N1B + t] - m * sc;
    }
    __syncthreads();
    for (int i = t; i < 32 * C; i += 256) {
        int c = i & 127;
        sxb[i>>7][c] = f2bf(ldE(Y, (long)row0 * C + i) * nsc[c] + nsh[c]);
    }
    __syncthreads();
    int lane = t & 63, w = t >> 6;
    int col = lane & 15, quad = lane >> 4;
    for (int tid = w; tid < 64; tid += 4) {
        int mt = tid & 1, nt = tid >> 1, n0 = nt * 16;
        f32x4 acc = {0.f, 0.f, 0.f, 0.f};
        const unsigned short* aB = &sxb[mt*16][0];
        const unsigned short* bB = wsB + B_LIN1 + n0 * C;
        #pragma unroll
        for (int kt = 0; kt < 4; ++kt) {
            bfrag8 a = ldfrag(aB, 136, lane, kt*32);
            bfrag8 b = ldfrag(bB, C, lane, kt*32);
            acc = __builtin_amdgcn_mfma_f32_16x16x32_bf16(a, b, acc, 0, 0, 0);
        }
        #pragma unroll
        for (int r = 0; r < 4; ++r) {
            int m = mt*16 + quad*4 + r;
            int n = n0 + col;
            sh[m][n] = f2bf(fmaxf(acc[r] + wsW[OFF_LIN1_B + n], 0.f));
        }
    }
    __syncthreads();
    f32x4 accT[4];
    #pragma unroll
    for (int i = 0; i < 4; ++i) {
        int tid = w + 4*i;
        int mt = tid & 1, nt = tid >> 1, n0 = nt * 16;
        f32x4 acc = {0.f, 0.f, 0.f, 0.f};
        const unsigned short* aB = &sh[mt*16][0];
        const unsigned short* bB = wsB + B_LIN2 + n0 * FF;
        #pragma unroll
        for (int kt = 0; kt < 16; ++kt) {
            bfrag8 a = ldfrag(aB, 520, lane, kt*32);
            bfrag8 b = ldfrag(bB, FF, lane, kt*32);
            acc = __builtin_amdgcn_mfma_f32_16x16x32_bf16(a, b, acc, 0, 0, 0);
        }
        accT[i] = acc;
    }
    __syncthreads();
    #pragma unroll
    for (int i = 0; i < 4; ++i) {
        int tid = w + 4*i;
        int mt = tid & 1, nt = tid >> 1, n0 = nt * 16;
        #pragma unroll
        for (int r = 0; r < 4; ++r) {
            int m = mt*16 + quad*4 + r;
            int n = n0 + col;
            syf[m][n] = accT[i][r] + wsW[OFF_LIN2_B + n] + bf2f(sxb[m][n]);
        }
    }
    __syncthreads();
    for (int i = t; i < 32 * C; i += 256)
        stE(Y, (long)row0 * C + i, syf[i>>7][i&127]);
    if (t < C) {
        float s = 0.f, sq = 0.f;
        for (int r = 0; r < 32; ++r) { float v = syf[r][t]; s += v; sq += v*v; }
        atomicAdd(&acc2[t], s);
        atomicAdd(&acc2[C+t], sq);
    }
}

// ---- bn2 + output linear + bn3 stats (MFMA) ----
template <typename T>
__global__ __launch_bounds__(256) void k_outl(
    const float* __restrict__ wsW, const unsigned short* __restrict__ wsB,
    T* __restrict__ Y, const float* __restrict__ acc2, float* __restrict__ acc3)
{
    __shared__ __align__(16) unsigned short sxb[32][136];
    __shared__ float syf[32][132];
    __shared__ float nsc[C], nsh[C];
    int t = threadIdx.x;
    int row0 = blockIdx.x * 32;
    if (t < C) {
        float m = acc2[t] * (1.0f/NPTS);
        float v = acc2[C+t] * (1.0f/NPTS) - m*m;
        float rs = rsqrtf(v + EPS);
        float sc = rs * wsW[OFF_N2G + t];
        nsc[t] = sc;
        nsh[t] = wsW[OFF_N2B + t] - m * sc;
    }
    __syncthreads();
    for (int i = t; i < 32 * C; i += 256) {
        int c = i & 127;
        sxb[i>>7][c] = f2bf(ldE(Y, (long)row0 * C + i) * nsc[c] + nsh[c]);
    }
    __syncthreads();
    int lane = t & 63, w = t >> 6;
    int col = lane & 15, quad = lane >> 4;
    for (int tid = w; tid < 16; tid += 4) {
        int mt = tid & 1, nt = tid >> 1, n0 = nt * 16;
        f32x4 acc = {0.f, 0.f, 0.f, 0.f};
        const unsigned short* aB = &sxb[mt*16][0];
        const unsigned short* bB = wsB + B_OUTL + n0 * C;
        #pragma unroll
        for (int kt = 0; kt < 4; ++kt) {
            bfrag8 a = ldfrag(aB, 136, lane, kt*32);
            bfrag8 b = ldfrag(bB, C, lane, kt*32);
            acc = __builtin_amdgcn_mfma_f32_16x16x32_bf16(a, b, acc, 0, 0, 0);
        }
        #pragma unroll
        for (int r = 0; r < 4; ++r) {
            int m = mt*16 + quad*4 + r;
            int n = n0 + col;
            syf[m][n] = acc[r] + wsW[OFF_OUTL_B + n];
        }
    }
    __syncthreads();
    for (int i = t; i < 32 * CO; i += 256)
        stE(Y, (long)row0 * CO + i, syf[i>>7][i&127]);
    if (t < CO) {
        float s = 0.f, sq = 0.f;
        for (int r = 0; r < 32; ++r) { float v = syf[r][t]; s += v; sq += v*v; }
        atomicAdd(&acc3[t], s);
        atomicAdd(&acc3[CO+t], sq);
    }
}

// ---- final BN + relu -> output ----
template <typename T>
__global__ __launch_bounds__(256) void k_final(
    const float* __restrict__ wsW, const T* __restrict__ Y,
    const float* __restrict__ acc3, const int* __restrict__ flagp,
    void* __restrict__ out)
{
    long i = (long)blockIdx.x * 256 + threadIdx.x;
    int c = (int)(i & (CO-1));
    float m = acc3[c] * (1.0f/NPTS);
    float v = acc3[CO+c] * (1.0f/NPTS) - m*m;
    float rs = rsqrtf(v + EPS);
    float y = (ldE(Y, i) - m) * rs * wsW[OFF_BOG + c] + wsW[OFF_BOB + c];
    y = fmaxf(y, 0.f);
    if (*flagp) ((unsigned short*)out)[i] = f2bf(y);
    else        ((float*)out)[i] = y;
}

extern "C" void kernel_launch(void* const* d_in, const int* in_sizes, int n_in,
                              void* d_out, int out_size, void* d_ws, size_t ws_size,
                              hipStream_t stream)
{
    char* base = (char*)d_ws;
    float* wsW = (float*)base;
    float* acc1 = wsW + WTOTAL;
    float* acc2 = acc1 + 256;
    float* acc3 = acc2 + 256;
    int* flagp = (int*)(wsW + WTOTAL + 768);
    float* coords = wsW + WTOTAL + 776;
    unsigned short* wsB = (unsigned short*)(base + OFF_WB_BYTES);

    const void* featv = d_in[0];
    const int* indices = (const int*)d_in[1];
    const int* key_idx = (const int*)d_in[2];

    hipMemsetAsync(acc1, 0, 768 * sizeof(float), stream);
    k_detect<<<1, 256, 0, stream>>>((const unsigned short*)d_in[0], flagp);

    static const int cnt[20] = {49152,384,16384,128,384,128,384,128,128,128,
                                128,128,65536,512,65536,128,16384,128,128,128};
    static const int bofs[20] = {B_INPROJ,-1,B_OUTW,-1,-1,-1,-1,-1,-1,-1,
                                 -1,-1,B_LIN1,-1,B_LIN2,-1,B_OUTL,-1,-1,-1};
    WTab tab;
    int off = 0;
    for (int j = 0; j < 20; ++j) {
        tab.src[j] = d_in[3 + j];
        tab.beg[j] = off;
        tab.end[j] = off + cnt[j];
        tab.bo[j] = bofs[j];
        off += cnt[j];
    }
    k_cvt_weights<<<WTOTAL/256, 256, 0, stream>>>(tab, wsW, wsB, flagp);

    size_t bigN = (size_t)NPTS * C;
    bool f32mode = (ws_size >= OFF_BIG_BYTES + 3 * bigN * 2 + bigN * 4);

    unsigned short* Qh = (unsigned short*)(base + OFF_BIG_BYTES);
    unsigned short* Kf = Qh + bigN;
    unsigned short* Vf = Kf + bigN;

    k_proj<unsigned short><<<NPTS/32, 256, 0, stream>>>(wsW, wsB, featv, flagp, indices, coords, Qh, Kf, Vf);

    if (f32mode) {
        float* Y = (float*)(Vf + bigN);
        k_attn<float><<<NPTS, 64, 0, stream>>>(wsW, wsB, coords, key_idx, Qh, Kf, Vf, Y);
        k_outproj<float><<<NPTS/32, 256, 0, stream>>>(wsW, wsB, featv, flagp, Y, acc1);
        k_ffn<float><<<NPTS/32, 256, 0, stream>>>(wsW, wsB, Y, acc1, acc2);
        k_outl<float><<<NPTS/32, 256, 0, stream>>>(wsW, wsB, Y, acc2, acc3);
        k_final<float><<<(NPTS*CO)/256, 256, 0, stream>>>(wsW, Y, acc3, flagp, d_out);
    } else {
        unsigned short* Y = Vf + bigN;
        k_attn<unsigned short><<<NPTS, 64, 0, stream>>>(wsW, wsB, coords, key_idx, Qh, Kf, Vf, Y);
        k_outproj<unsigned short><<<NPTS/32, 256, 0, stream>>>(wsW, wsB, featv, flagp, Y, acc1);
        k_ffn<unsigned short><<<NPTS/32, 256, 0, stream>>>(wsW, wsB, Y, acc1, acc2);
        k_outl<unsigned short><<<NPTS/32, 256, 0, stream>>>(wsW, wsB, Y, acc2, acc3);
        k_final<unsigned short><<<(NPTS*CO)/256, 256, 0, stream>>>(wsW, Y, acc3, flagp, d_out);
    }
}